// Round 8
// baseline (733.686 us; speedup 1.0000x reference)
//
#include <hip/hip_runtime.h>

// GNNLayer: 3 MLPs (node/message/final). BN folded into GEMM weights.
// bf16 storage, fp32 MFMA accumulation, fp32 stats.
// Round 8:
//  - k_gemm_msg6 = msg4's footprint (50 KB LDS, 3 blocks/CU) + msg5's
//    register-depth: PQ loads 2 tiles ahead in named reg sets, counted
//    vmcnt(8)/vmcnt(4) waits that never drain the in-flight prefetch.
//  - BN0 folds merged 3->1 (k_fold0, atomic bias accumulation onto
//    zero-init'd biasPQ), BN1 folds merged 2->1 (k_fold1): -3 launches.

typedef __attribute__((ext_vector_type(8))) short short8;
typedef __attribute__((ext_vector_type(4))) float f32x4;
typedef __attribute__((ext_vector_type(4))) unsigned int u32x4;

__device__ __forceinline__ unsigned short f2bu(float f) {
    unsigned int x = __float_as_uint(f);
    x += 0x7fffu + ((x >> 16) & 1u);
    return (unsigned short)(x >> 16);
}
__device__ __forceinline__ float b2f(unsigned short u) {
    return __uint_as_float(((unsigned int)u) << 16);
}
__device__ __forceinline__ float sigmoidf_(float v) {
    return 1.0f / (1.0f + __expf(-v));
}

// async global->LDS DMA, 16 B per lane; LDS dest = wave-uniform base + lane*16
__device__ __forceinline__ void gld16(const void* g, void* l) {
    __builtin_amdgcn_global_load_lds(
        (const __attribute__((address_space(1))) void*)g,
        (__attribute__((address_space(3))) void*)l, 16, 0, 0);
}

// pipeline barrier: drain DMA + LDS ops, raw barrier
__device__ __forceinline__ void pipe_barrier() {
    asm volatile("s_waitcnt vmcnt(0) lgkmcnt(0)" ::: "memory");
    __builtin_amdgcn_s_barrier();
    __builtin_amdgcn_sched_barrier(0);
}

__global__ __launch_bounds__(256) void k_zero4(float4* p, int n4) {
    int i = blockIdx.x * 256 + threadIdx.x;
    if (i < n4) p[i] = make_float4(0.f, 0.f, 0.f, 0.f);
}

// x fp32 -> bf16 copy + per-feature sum/sumsq (fused)
__global__ __launch_bounds__(256) void k_xcvt(const float* __restrict__ x,
                                              unsigned short* __restrict__ x16,
                                              float* __restrict__ ssum,
                                              float* __restrict__ ssq) {
    const int c = threadIdx.x;
    const int r0 = blockIdx.x * 64;
    float s = 0.f, q = 0.f;
    for (int r = r0; r < r0 + 64; ++r) {
        float v = x[(size_t)r * 256 + c];
        x16[(size_t)r * 256 + c] = f2bu(v);
        s += v; q += v * v;
    }
    atomicAdd(&ssum[c], s);
    atomicAdd(&ssq[c], q);
}

// BN0 fold, 3 weight sets in one launch (blockIdx.y):
//  y=0: An = s.nW0 (N=512,Kc=256), bias_n = red + nc0   (plain write)
//  y=1: Btm top, biasPQ += red + mc0                    (atomic, order-free)
//  y=2: Btm bottom, biasPQ += red                       (atomic)
__global__ __launch_bounds__(256) void k_fold0(const float* __restrict__ nW0, const float* __restrict__ ng0,
                                               const float* __restrict__ nb0, const float* __restrict__ nc0,
                                               const float* __restrict__ mW0, const float* __restrict__ mg0,
                                               const float* __restrict__ mb0, const float* __restrict__ mc0,
                                               const float* __restrict__ ssum, const float* __restrict__ ssq,
                                               unsigned short* __restrict__ An, float* __restrict__ bias_n,
                                               unsigned short* __restrict__ Btm, float* __restrict__ biasPQ) {
    const int j = blockIdx.x;          // 0..511
    const int y = blockIdx.y;          // 0..2
    const int k = threadIdx.x;         // 0..255 == Kc
    const float* W; const float* g; const float* b; unsigned short* Bt;
    if (y == 0)      { W = nW0;             g = ng0;       b = nb0;       Bt = An; }
    else if (y == 1) { W = mW0;             g = mg0;       b = mb0;       Bt = Btm; }
    else             { W = mW0 + 256 * 512; g = mg0 + 256; b = mb0 + 256; Bt = Btm + 512 * 256; }
    const float inv = 1.f / 65536.f;
    float mu  = ssum[k] * inv;
    float var = ssq[k] * inv - mu * mu;
    float s   = g[k] * rsqrtf(var + 1e-5f);
    float tt  = b[k] - mu * s;
    float wv  = W[(size_t)k * 512 + j];
    Bt[(size_t)j * 256 + k] = f2bu(s * wv);
    __shared__ float red[256];
    red[k] = tt * wv;
    __syncthreads();
    for (int s2 = 128; s2 > 0; s2 >>= 1) {
        if (k < s2) red[k] += red[k + s2];
        __syncthreads();
    }
    if (k == 0) {
        if (y == 0)      bias_n[j] = red[0] + nc0[j];
        else if (y == 1) atomicAdd(&biasPQ[j], red[0] + mc0[j]);
        else             atomicAdd(&biasPQ[j], red[0]);
    }
}

// BN1 fold, 2 weight sets in one launch (blockIdx.y): node (inv1) / msg (invM)
__global__ __launch_bounds__(256) void k_fold1(const float* __restrict__ nW1, const float* __restrict__ ng1,
                                               const float* __restrict__ nb1, const float* __restrict__ nc1,
                                               const float* __restrict__ mW1, const float* __restrict__ mg1,
                                               const float* __restrict__ mb1, const float* __restrict__ mc1,
                                               const float* __restrict__ shn_s, const float* __restrict__ shn_q,
                                               const float* __restrict__ shm_s, const float* __restrict__ shm_q,
                                               unsigned short* __restrict__ A1n, float* __restrict__ b1n,
                                               unsigned short* __restrict__ A1m, float* __restrict__ b1m) {
    const int j = blockIdx.x;      // 0..255
    const int y = blockIdx.y;      // 0..1
    const int t = threadIdx.x;
    const float* W  = y ? mW1 : nW1;
    const float* g  = y ? mg1 : ng1;
    const float* b  = y ? mb1 : nb1;
    const float* cv = y ? mc1 : nc1;
    const float* ss = y ? shm_s : shn_s;
    const float* sq = y ? shm_q : shn_q;
    unsigned short* Bt = y ? A1m : A1n;
    float* bias = y ? b1m : b1n;
    const float inv = y ? (1.f / 196608.f) : (1.f / 65536.f);
    float part = 0.f;
    for (int k = t; k < 512; k += 256) {
        float mu  = ss[k] * inv;
        float var = sq[k] * inv - mu * mu;
        float s   = g[k] * rsqrtf(var + 1e-5f);
        float tt  = b[k] - mu * s;
        float wv  = W[(size_t)k * 256 + j];
        Bt[(size_t)j * 512 + k] = f2bu(s * wv);
        part += tt * wv;
    }
    __shared__ float red[256];
    red[t] = part;
    __syncthreads();
    for (int s2 = 128; s2 > 0; s2 >>= 1) {
        if (t < s2) red[t] += red[t + s2];
        __syncthreads();
    }
    if (t == 0) bias[j] = red[0] + cv[j];
}

// generic fold (final MLP): Bt[j][k] = s_k*W[k][j]; bias[j] = red + cvec[j]
__global__ __launch_bounds__(256) void k_fold(const float* __restrict__ W,      // [Kc][N]
                                              const float* __restrict__ gamma,
                                              const float* __restrict__ beta,
                                              const float* __restrict__ ssum,
                                              const float* __restrict__ ssq,
                                              const float* __restrict__ cvec,
                                              float inv_count, int N, int Kc,
                                              unsigned short* __restrict__ Bt,  // [N][Kc]
                                              float* __restrict__ bias, int bias_add) {
    const int j = blockIdx.x;
    const int t = threadIdx.x;
    float part = 0.f;
    for (int k = t; k < Kc; k += 256) {
        float mu  = ssum[k] * inv_count;
        float var = ssq[k] * inv_count - mu * mu;
        float s   = gamma[k] * rsqrtf(var + 1e-5f);
        float tt  = beta[k] - mu * s;
        float w   = W[(size_t)k * N + j];
        Bt[(size_t)j * Kc + k] = f2bu(s * w);
        part += tt * w;
    }
    __shared__ float red[256];
    red[t] = part;
    __syncthreads();
    for (int s2 = 128; s2 > 0; s2 >>= 1) {
        if (t < s2) red[t] += red[t + s2];
        __syncthreads();
    }
    if (t == 0) {
        if (bias_add) atomicAdd(&bias[j], red[0]);
        else bias[j] = red[0] + cvec[j];
    }
}

// 128x128-tile bf16 MFMA GEMM, A [M][lda] bf16, Bt [N][K] bf16.
// global_load_lds width=16 staging, 3-buffer counted-vmcnt pipeline.
// EPI: 1 bias+relu+stats bf16; 2 bias+sigmoid+stats bf16; 4 bias+sigmoid f32
template <int EPI>
__global__ __launch_bounds__(256) void k_gemm(const unsigned short* __restrict__ A, int lda,
                                              const unsigned short* __restrict__ Bt,
                                              void* __restrict__ C, int ldc,
                                              const float* __restrict__ bias,
                                              float* __restrict__ ssum, float* __restrict__ ssq,
                                              int K) {
    const int n0 = blockIdx.x * 128;
    const int m0 = blockIdx.y * 128;
    const int tid = threadIdx.x;
    const int w = tid >> 6;
    const int lane = tid & 63;
    const int q = lane >> 4;
    const int l = lane & 15;
    const int wm = w >> 1;
    const int wn = w & 1;

    __shared__ __align__(16) unsigned short lA[3][128 * 32];  // [m][k]
    __shared__ __align__(16) unsigned short lB[3][128 * 32];  // [n][k]
    __shared__ float s_sum[128];
    __shared__ float s_sq[128];

    if ((EPI == 1 || EPI == 2) && tid < 128) { s_sum[tid] = 0.f; s_sq[tid] = 0.f; }

    f32x4 acc[4][4] = {};

    const int rsub = tid >> 2;          // 0..63
    const int ksub = (tid & 3) * 8;     // 0,8,16,24
    const unsigned short* gA = A + (size_t)(m0 + rsub) * lda + ksub;
    const unsigned short* gB = Bt + (size_t)(n0 + rsub) * K + ksub;
    const unsigned wofs = (unsigned)(tid >> 6) * 1024;  // wave LDS base, bytes

    auto stage = [&](int buf, int k0) {   // 4 DMA ops per wave
        char* la = (char*)lA[buf] + wofs;
        char* lb = (char*)lB[buf] + wofs;
        gld16(gA + k0, la);
        gld16(gA + (size_t)64 * lda + k0, la + 4096);
        gld16(gB + k0, lb);
        gld16(gB + (size_t)64 * K + k0, lb + 4096);
    };

    const int nt = K >> 5;
    stage(0, 0);
    if (nt > 1) stage(1, 32);

    int cur = 0;
    for (int t = 0; t < nt; ++t) {
        if (t + 1 < nt) { asm volatile("s_waitcnt vmcnt(4)" ::: "memory"); }
        else            { asm volatile("s_waitcnt vmcnt(0)" ::: "memory"); }
        __builtin_amdgcn_s_barrier();
        __builtin_amdgcn_sched_barrier(0);
        if (t + 2 < nt) {
            int b2 = cur + 2; if (b2 >= 3) b2 -= 3;
            stage(b2, (t + 2) << 5);   // overwrites buf t-1: safe, all reads done
        }
        short8 av[4], bv[4];
#pragma unroll
        for (int i = 0; i < 4; ++i)
            av[i] = *(const short8*)(&lA[cur][(wm * 64 + i * 16 + l) * 32 + q * 8]);
#pragma unroll
        for (int j = 0; j < 4; ++j)
            bv[j] = *(const short8*)(&lB[cur][(wn * 64 + j * 16 + l) * 32 + q * 8]);
#pragma unroll
        for (int i = 0; i < 4; ++i)
#pragma unroll
            for (int j = 0; j < 4; ++j)
                acc[i][j] = __builtin_amdgcn_mfma_f32_16x16x32_bf16(av[i], bv[j], acc[i][j], 0, 0, 0);
        cur = (cur == 2) ? 0 : cur + 1;
    }

#pragma unroll
    for (int j = 0; j < 4; ++j) {
        const int colL = wn * 64 + j * 16 + l;
        const int col = n0 + colL;
        const float bb = bias[col];
        float psum = 0.f, psq = 0.f;
#pragma unroll
        for (int i = 0; i < 4; ++i) {
            const int rowL = wm * 64 + i * 16 + q * 4;
#pragma unroll
            for (int r = 0; r < 4; ++r) {
                float v = acc[i][j][r] + bb;
                if (EPI == 1) v = fmaxf(v, 0.f);
                if (EPI == 2 || EPI == 4) v = sigmoidf_(v);
                const size_t off = (size_t)(m0 + rowL + r) * ldc + col;
                if (EPI == 4) ((float*)C)[off] = v;
                else ((unsigned short*)C)[off] = f2bu(v);
                psum += v; psq += v * v;
            }
        }
        if (EPI == 1 || EPI == 2) {
            atomicAdd(&s_sum[colL], psum);
            atomicAdd(&s_sq[colL], psq);
        }
    }
    if (EPI == 1 || EPI == 2) {
        __syncthreads();
        if (tid < 128) {
            atomicAdd(&ssum[n0 + tid], s_sum[tid]);
            atomicAdd(&ssq[n0 + tid], s_sq[tid]);
        }
    }
}

// Dual-tile PQ GEMM + fused h_m stats (unchanged from round 6).
template <int STATS>
__global__ __launch_bounds__(256) void k_gemm_pq(const unsigned short* __restrict__ A,   // x16 chunk [G][256]
                                                 const unsigned short* __restrict__ Bt,  // Btm [1024][256]
                                                 unsigned short* __restrict__ PQ,        // [G][1024]
                                                 const float* __restrict__ biasP,        // biasPQ [512]
                                                 float* __restrict__ ssum,               // shm_s
                                                 float* __restrict__ ssq) {              // shm_q
    const int K = 256;
    const int f0 = blockIdx.x * 128;
    const int m0 = blockIdx.y * 128;
    const int tid = threadIdx.x;
    const int w = tid >> 6;
    const int lane = tid & 63;
    const int q = lane >> 4;
    const int l = lane & 15;
    const int wm = w >> 1;
    const int wn = w & 1;

    __shared__ __align__(16) unsigned short lA[2][128 * 32];  // 8 KB each
    __shared__ __align__(16) unsigned short lB[2][256 * 32];  // 16 KB each
    __shared__ float s_sum[128];
    __shared__ float s_sq[128];

    if (STATS && tid < 128) { s_sum[tid] = 0.f; s_sq[tid] = 0.f; }

    f32x4 accP[4][4] = {};
    f32x4 accQ[4][4] = {};

    const int rsub = tid >> 2;          // 0..63
    const int ksub = (tid & 3) * 8;     // 0,8,16,24
    const unsigned short* gA  = A  + (size_t)(m0 + rsub) * 256 + ksub;
    const unsigned short* gBP = Bt + (size_t)(f0 + rsub) * K + ksub;
    const unsigned short* gBQ = Bt + (size_t)(512 + f0 + rsub) * K + ksub;
    const unsigned wofs = (unsigned)w * 1024;

    auto stage = [&](int buf, int k0) {   // 6 DMA ops per wave
        char* la = (char*)lA[buf] + wofs;
        char* lb = (char*)lB[buf] + wofs;
        gld16(gA + k0, la);
        gld16(gA + (size_t)64 * 256 + k0, la + 4096);
        gld16(gBP + k0, lb);
        gld16(gBP + (size_t)64 * K + k0, lb + 4096);
        gld16(gBQ + k0, lb + 8192);
        gld16(gBQ + (size_t)64 * K + k0, lb + 12288);
    };

    stage(0, 0);
    pipe_barrier();

    const int nt = K >> 5;  // 8
    int cur = 0;
    for (int t = 0; t < nt; ++t) {
        if (t + 1 < nt) stage(cur ^ 1, (t + 1) << 5);  // DMA lands during MFMA
        short8 av[4], bvP[4], bvQ[4];
#pragma unroll
        for (int i = 0; i < 4; ++i)
            av[i] = *(const short8*)(&lA[cur][(wm * 64 + i * 16 + l) * 32 + q * 8]);
#pragma unroll
        for (int j = 0; j < 4; ++j) {
            bvP[j] = *(const short8*)(&lB[cur][(wn * 64 + j * 16 + l) * 32 + q * 8]);
            bvQ[j] = *(const short8*)(&lB[cur][(128 + wn * 64 + j * 16 + l) * 32 + q * 8]);
        }
#pragma unroll
        for (int i = 0; i < 4; ++i)
#pragma unroll
            for (int j = 0; j < 4; ++j) {
                accP[i][j] = __builtin_amdgcn_mfma_f32_16x16x32_bf16(av[i], bvP[j], accP[i][j], 0, 0, 0);
                accQ[i][j] = __builtin_amdgcn_mfma_f32_16x16x32_bf16(av[i], bvQ[j], accQ[i][j], 0, 0, 0);
            }
        if (t + 1 < nt) pipe_barrier();
        cur ^= 1;
    }

#pragma unroll
    for (int j = 0; j < 4; ++j) {
        const int colL = wn * 64 + j * 16 + l;   // 0..127
        const int f = f0 + colL;
        const float bb = biasP[f];
        float s = 0.f, qq = 0.f;
#pragma unroll
        for (int i = 0; i < 4; ++i) {
            const int rowb = m0 + wm * 64 + i * 16 + q * 4;   // %4==0: one graph
            float p[4], qv[4];
#pragma unroll
            for (int r = 0; r < 4; ++r) {
                p[r]  = accP[i][j][r] + bb;
                qv[r] = accQ[i][j][r];
                PQ[(size_t)(rowb + r) * 1024 + f]       = f2bu(p[r]);
                PQ[(size_t)(rowb + r) * 1024 + 512 + f] = f2bu(qv[r]);
            }
            if (STATS) {
#pragma unroll
                for (int si = 0; si < 4; ++si)
#pragma unroll
                    for (int di = 0; di < 4; ++di) {
                        if (si == di) continue;
                        float v = fmaxf(p[si] + qv[di], 0.f);
                        s += v; qq += v * v;
                    }
            }
        }
        if (STATS) {
            atomicAdd(&s_sum[colL], s);
            atomicAdd(&s_sq[colL], qq);
        }
    }
    if (STATS) {
        __syncthreads();
        if (tid < 128) {
            atomicAdd(&ssum[f0 + tid], s_sum[tid]);
            atomicAdd(&ssq[f0 + tid], s_sq[tid]);
        }
    }
}

// Fused message GEMM + in-register mean + bf16 store + column stats.
// 128x256 tile, wave grid 2x2, acc[4][8]. msg4 footprint (50 KB LDS,
// 3 blocks/CU) + 2-tile-ahead PQ register prefetch with counted waits:
// per iter: {stageB(t+1), loadPQ(t+2)} -> MFMA(t) -> vmcnt(8) ->
// buildA(t+1) -> vmcnt(4)+lgkmcnt(0) -> barrier. Prefetch never drained.
__global__ __launch_bounds__(256) void k_gemm_msg6(const unsigned short* __restrict__ PQ,  // [G][1024] chunk-local
                                                   const unsigned short* __restrict__ Bt,  // A1m [256][512]
                                                   unsigned short* __restrict__ inf_,      // chunk-offset, [G][512] bf16
                                                   const float* __restrict__ bias,         // b1m [256]
                                                   float* __restrict__ ssum,               // sif_s+256
                                                   float* __restrict__ ssq) {              // sif_q+256
    const int K = 512;
    const int m0 = blockIdx.x * 128;          // padded chunk-local msg row base
    const int tid = threadIdx.x;
    const int w = tid >> 6;
    const int lane = tid & 63;
    const int q = lane >> 4;
    const int l = lane & 15;
    const int wm = w >> 1;                    // row half
    const int wn = w & 1;                     // col half (128 cols each)

    __shared__ __align__(16) unsigned short lA[2][128 * 32];  // 8 KB each
    __shared__ __align__(16) unsigned short lB[2][256 * 32];  // 16 KB each
    __shared__ float s_sum[256];
    __shared__ float s_sq[256];

    s_sum[tid] = 0.f; s_sq[tid] = 0.f;

    f32x4 acc[4][8] = {};

    const int rsub = tid >> 2;          // 0..63
    const int ksub = (tid & 3) * 8;     // 0,8,16,24
    unsigned aP[2], aQ[2], wAo[2];
#pragma unroll
    for (int t = 0; t < 2; ++t) {
        int row = m0 + t * 64 + rsub;    // padded chunk-local msg row
        int node = row >> 2;             // chunk-local node
        int slot = row & 3;
        int si = node & 3;
        int di = slot + (slot >= si ? 1 : 0);   // slot==3 -> di=4: benign OOB within ws
        aP[t] = (unsigned)node * 1024 + ksub;
        aQ[t] = (unsigned)(node - si + di) * 1024 + 512 + ksub;
        wAo[t] = (unsigned)((t * 64 + rsub) * 32 + ksub);
    }
    const unsigned short* gB = Bt + (size_t)rsub * K + ksub;
    const unsigned wofs = (unsigned)w * 1024;   // bytes

    auto loadPQ = [&](int k0, short8 (&p8)[2], short8 (&q8)[2]) {
#pragma unroll
        for (int t = 0; t < 2; ++t) {
            p8[t] = *(const short8*)(PQ + aP[t] + k0);
            q8[t] = *(const short8*)(PQ + aQ[t] + k0);
        }
    };
    auto buildA = [&](int abuf, const short8 (&p8)[2], const short8 (&q8)[2]) {
        unsigned short* la = lA[abuf];
#pragma unroll
        for (int t = 0; t < 2; ++t) {
            u32x4 pu = __builtin_bit_cast(u32x4, p8[t]);
            u32x4 qu = __builtin_bit_cast(u32x4, q8[t]);
            u32x4 ou;
#pragma unroll
            for (int i = 0; i < 4; ++i) {
                float pl = __uint_as_float(pu[i] << 16);
                float ph = __uint_as_float(pu[i] & 0xffff0000u);
                float ql = __uint_as_float(qu[i] << 16);
                float qh = __uint_as_float(qu[i] & 0xffff0000u);
                float sl = fmaxf(pl + ql, 0.f);
                float sh = fmaxf(ph + qh, 0.f);
                unsigned r;
                asm("v_cvt_pk_bf16_f32 %0, %1, %2" : "=v"(r) : "v"(sl), "v"(sh));
                ou[i] = r;
            }
            *(short8*)(la + wAo[t]) = __builtin_bit_cast(short8, ou);
        }
    };
    auto stageB = [&](int buf, int k0) {   // 4 DMA ops per wave, 256 rows/step
        char* lb = (char*)lB[buf] + wofs;
#pragma unroll
        for (int t = 0; t < 4; ++t)
            gld16(gB + (size_t)(t * 64) * K + k0, lb + t * 4096);
    };
    auto mfma_tile = [&](int cur) {
        short8 av[4], bv[8];
#pragma unroll
        for (int i = 0; i < 4; ++i)
            av[i] = *(const short8*)(&lA[cur][(wm * 64 + i * 16 + l) * 32 + q * 8]);
#pragma unroll
        for (int j = 0; j < 8; ++j)
            bv[j] = *(const short8*)(&lB[cur][(wn * 128 + j * 16 + l) * 32 + q * 8]);
#pragma unroll
        for (int i = 0; i < 4; ++i)
#pragma unroll
            for (int j = 0; j < 8; ++j)
                acc[i][j] = __builtin_amdgcn_mfma_f32_16x16x32_bf16(av[i], bv[j], acc[i][j], 0, 0, 0);
    };

    const int nt = 16;
    short8 pA[2], qA[2], pB[2], qB[2];
    // prologue: build tile0 into lA[0]/lB[0]; leave tile1's reg loads in flight
    loadPQ(0, pA, qA);                                         // 4
    stageB(0, 0);                                              // 4 -> 8
    asm volatile("s_waitcnt vmcnt(4)" ::: "memory");           // tile0 regs done
    buildA(0, pA, qA);
    loadPQ(32, pA, qA);                                        // tile1 regs -> 8
    asm volatile("s_waitcnt vmcnt(4) lgkmcnt(0)" ::: "memory");// stageB(0) + lA writes done
    __builtin_amdgcn_s_barrier();
    __builtin_amdgcn_sched_barrier(0);

    // invariant at iter t: lA[t&1],lB[t&1] published; outstanding = pCur regs (4)
    auto iter = [&](int t, short8 (&pc)[2], short8 (&qc)[2],
                    short8 (&pn)[2], short8 (&qn)[2]) {
        const int cur = t & 1;
        if (t + 1 < nt) stageB(cur ^ 1, (t + 1) << 5);         // 4
        if (t + 2 < nt) loadPQ((t + 2) << 5, pn, qn);          // 4
        mfma_tile(cur);
        if (t + 1 < nt) {
            if (t + 2 < nt) asm volatile("s_waitcnt vmcnt(8)" ::: "memory"); // pc done; newer 8 alive
            else            asm volatile("s_waitcnt vmcnt(4)" ::: "memory"); // pc done; stageB alive
            buildA(cur ^ 1, pc, qc);
            if (t + 2 < nt) asm volatile("s_waitcnt vmcnt(4) lgkmcnt(0)" ::: "memory"); // stageB done; pn alive
            else            asm volatile("s_waitcnt vmcnt(0) lgkmcnt(0)" ::: "memory");
            __builtin_amdgcn_s_barrier();
            __builtin_amdgcn_sched_barrier(0);
        }
    };

    for (int t = 0; t < nt; t += 2) {
        iter(t,     pA, qA, pB, qB);   // consume tile t+1 regs (A), prefetch t+2 -> B
        iter(t + 1, pB, qB, pA, qA);   // consume tile t+2 regs (B), prefetch t+3 -> A
    }

#pragma unroll
    for (int j = 0; j < 8; ++j) {
        const int colL = wn * 128 + j * 16 + l;
        const float bb = bias[colL];
        float psum = 0.f, psq = 0.f;
#pragma unroll
        for (int i = 0; i < 4; ++i) {
            const int g = (m0 >> 2) + wm * 16 + i * 4 + q;   // chunk-local node row
            float s0 = sigmoidf_(acc[i][j][0] + bb);
            float s1 = sigmoidf_(acc[i][j][1] + bb);
            float s2 = sigmoidf_(acc[i][j][2] + bb);
            float vm = (s0 + s1 + s2) * (1.f / 3.f);
            inf_[(size_t)g * 512 + 256 + colL] = f2bu(vm);
            psum += vm; psq += vm * vm;
        }
        atomicAdd(&s_sum[colL], psum);
        atomicAdd(&s_sq[colL], psq);
    }
    __syncthreads();
    atomicAdd(&ssum[tid], s_sum[tid]);
    atomicAdd(&ssq[tid], s_sq[tid]);
}

extern "C" void kernel_launch(void* const* d_in, const int* in_sizes, int n_in,
                              void* d_out, int out_size, void* d_ws, size_t ws_size,
                              hipStream_t stream) {
    const float* x   = (const float*)d_in[0];
    const float* ng0 = (const float*)d_in[1];
    const float* nb0 = (const float*)d_in[2];
    const float* nW0 = (const float*)d_in[3];
    const float* nc0 = (const float*)d_in[4];
    const float* ng1 = (const float*)d_in[5];
    const float* nb1 = (const float*)d_in[6];
    const float* nW1 = (const float*)d_in[7];
    const float* nc1 = (const float*)d_in[8];
    const float* mg0 = (const float*)d_in[9];
    const float* mb0 = (const float*)d_in[10];
    const float* mW0 = (const float*)d_in[11];
    const float* mc0 = (const float*)d_in[12];
    const float* mg1 = (const float*)d_in[13];
    const float* mb1 = (const float*)d_in[14];
    const float* mW1 = (const float*)d_in[15];
    const float* mc1 = (const float*)d_in[16];
    const float* fg0 = (const float*)d_in[17];
    const float* fb0 = (const float*)d_in[18];
    const float* fW0 = (const float*)d_in[19];
    const float* fc0 = (const float*)d_in[20];
    const float* fg1 = (const float*)d_in[21];
    const float* fb1 = (const float*)d_in[22];
    const float* fW1 = (const float*)d_in[23];
    const float* fc1 = (const float*)d_in[24];

    char* ws = (char*)d_ws;
    const size_t MiB = 1024 * 1024;

    // chunk count for PQ: peak ws = 100 + 128/Cq MiB (x16 adds 32 MiB)
    int Cq = 1;
    while (Cq < 8 && (100 + 128 / Cq) * MiB > ws_size) Cq *= 2;
    const int G = 65536 / Cq;  // node rows per chunk (multiple of 128)

    // header [0,4MiB): stats (zeroed) + biases + folded weights
    float* stat = (float*)ws;
    float* sx_s   = stat + 0;     // 256
    float* sx_q   = stat + 256;   // 256
    float* shn_s  = stat + 512;   // 512
    float* shn_q  = stat + 1024;
    float* shm_s  = stat + 1536;
    float* shm_q  = stat + 2048;
    float* sif_s  = stat + 2560;
    float* sif_q  = stat + 3072;
    float* shf_s  = stat + 3584;
    float* shf_q  = stat + 4096;  // -> 4608
    float* biasPQ = stat + 4608;  // 1024, upper 512 stay zero
    // zeroed region ends at 5632 floats
    float* bias_n = stat + 5632;  // 512
    float* b1n    = stat + 6144;  // 256
    float* b1m    = stat + 6400;  // 256
    float* b0f    = stat + 6656;  // 512
    float* b1f    = stat + 7168;  // 256

    unsigned short* An  = (unsigned short*)(ws + 256 * 1024);  // [512][256]
    unsigned short* Btm = An + 512 * 256;                      // [1024][256]
    unsigned short* A1n = Btm + 1024 * 256;                    // [256][512]
    unsigned short* A1m = A1n + 256 * 512;                     // [256][512]
    unsigned short* A0f = A1m + 256 * 512;                     // [512][512]
    unsigned short* A1f = A0f + 512 * 512;                     // [256][512]

    // [4,68): hn (bf16, live gemm1..gemm2n) -> hf (bf16, live gemm3..gemm4)
    // [68, 68+128/Cq): PQ chunk buffer
    // [68+128/Cq, +32): x16 bf16 [65536][256]
    unsigned short* hn    = (unsigned short*)(ws + 4 * MiB);
    unsigned short* hf    = (unsigned short*)(ws + 4 * MiB);
    unsigned short* PQbuf = (unsigned short*)(ws + 68 * MiB);
    unsigned short* x16   = (unsigned short*)(ws + (68 + 128 / Cq) * MiB);
    unsigned short* inf   = (unsigned short*)d_out;  // [65536,512] bf16, dead before gemm4

    const float inv1 = 1.f / 65536.f;

    // zero stats + biasPQ (5632 floats = 1408 float4)
    k_zero4<<<6, 256, 0, stream>>>((float4*)stat, 1408);

    // x -> bf16 + column stats (fused)
    k_xcvt<<<1024, 256, 0, stream>>>(x, x16, sx_s, sx_q);

    // fold BN0: 3 weight sets in one launch (msg BN0 stats == node BN0 stats:
    // each node appears exactly 3x as src and 3x as dst across the 12 pairs)
    k_fold0<<<dim3(512, 3), 256, 0, stream>>>(nW0, ng0, nb0, nc0, mW0, mg0, mb0, mc0,
                                              sx_s, sx_q, An, bias_n, Btm, biasPQ);

    // h_n = relu(x16 @ An + bias_n), BN1_n stats
    k_gemm<1><<<dim3(4, 512), 256, 0, stream>>>(x16, 256, An, hn, 512, bias_n, shn_s, shn_q, 256);

    // PQ chunks: dual-tile P/Q GEMM with fused h_m stats
    for (int c = 0; c < Cq; ++c) {
        k_gemm_pq<1><<<dim3(4, G / 128), 256, 0, stream>>>(
            x16 + (size_t)c * G * 256, Btm, PQbuf, biasPQ, shm_s, shm_q);
    }

    // fold BN1: both sets in one launch
    k_fold1<<<dim3(256, 2), 256, 0, stream>>>(nW1, ng1, nb1, nc1, mW1, mg1, mb1, mc1,
                                              shn_s, shn_q, shm_s, shm_q, A1n, b1n, A1m, b1m);

    // x_node = sigmoid(hn @ A1n + b1n) -> in_f[:,0:256] (in d_out), f-BN0 stats
    k_gemm<2><<<dim3(2, 512), 256, 0, stream>>>(hn, 512, A1n, inf, 512, b1n, sif_s, sif_q, 512);

    // x_agg: padded msg GEMM -> in_f[:,256:512] bf16 + f-BN0 stats (cols 256..511)
    for (int c = 0; c < Cq; ++c) {
        if (Cq > 1)  // recompute PQ chunk without stats (Cq==1 kept the full PQ)
            k_gemm_pq<0><<<dim3(4, G / 128), 256, 0, stream>>>(
                x16 + (size_t)c * G * 256, Btm, PQbuf, biasPQ, nullptr, nullptr);
        k_gemm_msg6<<<dim3(G / 32), 256, 0, stream>>>(
            PQbuf, A1m, inf + (size_t)c * G * 512, b1m, sif_s + 256, sif_q + 256);
    }

    // final MLP
    k_fold<<<512, 256, 0, stream>>>(fW0, fg0, fb0, sif_s, sif_q, fc0, inv1, 512, 512, A0f, b0f, 0);
    k_gemm<1><<<dim3(4, 512), 256, 0, stream>>>(inf, 512, A0f, hf, 512, b0f, shf_s, shf_q, 512);
    k_fold<<<256, 256, 0, stream>>>(fW1, fg1, fb1, shf_s, shf_q, fc1, inv1, 256, 512, A1f, b1f, 0);
    k_gemm<4><<<dim3(2, 512), 256, 0, stream>>>(hf, 512, A1f, d_out, 256, b1f, nullptr, nullptr, 512);

    (void)in_sizes; (void)n_in; (void)out_size;
}

// Round 9
// 656.902 us; speedup vs baseline: 1.1169x; 1.1169x over previous
//
#include <hip/hip_runtime.h>

// GNNLayer: 3 MLPs (node/message/final). BN folded into GEMM weights.
// bf16 storage, fp32 MFMA accumulation, fp32 stats.
// Round 9: revert msg kernel to the proven msg4 (112 VGPR, 2-buffer, 50 KB
// LDS, 3 blocks/CU) -- rounds 7/8 proved deeper pipelines cost more
// occupancy than they add ILP. Reorder: msg GEMM launches right after
// k_fold1 so PQbuf is still L3-resident from its writer (R5 vs R6 showed
// a 30 us L3-eviction penalty when other GEMMs run in between). Fold
// merges (k_fold0 3-in-1, k_fold1 2-in-1) kept.

typedef __attribute__((ext_vector_type(8))) short short8;
typedef __attribute__((ext_vector_type(4))) float f32x4;
typedef __attribute__((ext_vector_type(4))) unsigned int u32x4;

__device__ __forceinline__ unsigned short f2bu(float f) {
    unsigned int x = __float_as_uint(f);
    x += 0x7fffu + ((x >> 16) & 1u);
    return (unsigned short)(x >> 16);
}
__device__ __forceinline__ float b2f(unsigned short u) {
    return __uint_as_float(((unsigned int)u) << 16);
}
__device__ __forceinline__ float sigmoidf_(float v) {
    return 1.0f / (1.0f + __expf(-v));
}

// async global->LDS DMA, 16 B per lane; LDS dest = wave-uniform base + lane*16
__device__ __forceinline__ void gld16(const void* g, void* l) {
    __builtin_amdgcn_global_load_lds(
        (const __attribute__((address_space(1))) void*)g,
        (__attribute__((address_space(3))) void*)l, 16, 0, 0);
}

// pipeline barrier: drain DMA + LDS ops, raw barrier
__device__ __forceinline__ void pipe_barrier() {
    asm volatile("s_waitcnt vmcnt(0) lgkmcnt(0)" ::: "memory");
    __builtin_amdgcn_s_barrier();
    __builtin_amdgcn_sched_barrier(0);
}

__global__ __launch_bounds__(256) void k_zero4(float4* p, int n4) {
    int i = blockIdx.x * 256 + threadIdx.x;
    if (i < n4) p[i] = make_float4(0.f, 0.f, 0.f, 0.f);
}

// x fp32 -> bf16 copy + per-feature sum/sumsq (fused)
__global__ __launch_bounds__(256) void k_xcvt(const float* __restrict__ x,
                                              unsigned short* __restrict__ x16,
                                              float* __restrict__ ssum,
                                              float* __restrict__ ssq) {
    const int c = threadIdx.x;
    const int r0 = blockIdx.x * 64;
    float s = 0.f, q = 0.f;
    for (int r = r0; r < r0 + 64; ++r) {
        float v = x[(size_t)r * 256 + c];
        x16[(size_t)r * 256 + c] = f2bu(v);
        s += v; q += v * v;
    }
    atomicAdd(&ssum[c], s);
    atomicAdd(&ssq[c], q);
}

// BN0 fold, 3 weight sets in one launch (blockIdx.y):
//  y=0: An = s.nW0 (N=512,Kc=256), bias_n = red + nc0   (plain write)
//  y=1: Btm top, biasPQ += red + mc0                    (atomic, order-free)
//  y=2: Btm bottom, biasPQ += red                       (atomic)
__global__ __launch_bounds__(256) void k_fold0(const float* __restrict__ nW0, const float* __restrict__ ng0,
                                               const float* __restrict__ nb0, const float* __restrict__ nc0,
                                               const float* __restrict__ mW0, const float* __restrict__ mg0,
                                               const float* __restrict__ mb0, const float* __restrict__ mc0,
                                               const float* __restrict__ ssum, const float* __restrict__ ssq,
                                               unsigned short* __restrict__ An, float* __restrict__ bias_n,
                                               unsigned short* __restrict__ Btm, float* __restrict__ biasPQ) {
    const int j = blockIdx.x;          // 0..511
    const int y = blockIdx.y;          // 0..2
    const int k = threadIdx.x;         // 0..255 == Kc
    const float* W; const float* g; const float* b; unsigned short* Bt;
    if (y == 0)      { W = nW0;             g = ng0;       b = nb0;       Bt = An; }
    else if (y == 1) { W = mW0;             g = mg0;       b = mb0;       Bt = Btm; }
    else             { W = mW0 + 256 * 512; g = mg0 + 256; b = mb0 + 256; Bt = Btm + 512 * 256; }
    const float inv = 1.f / 65536.f;
    float mu  = ssum[k] * inv;
    float var = ssq[k] * inv - mu * mu;
    float s   = g[k] * rsqrtf(var + 1e-5f);
    float tt  = b[k] - mu * s;
    float wv  = W[(size_t)k * 512 + j];
    Bt[(size_t)j * 256 + k] = f2bu(s * wv);
    __shared__ float red[256];
    red[k] = tt * wv;
    __syncthreads();
    for (int s2 = 128; s2 > 0; s2 >>= 1) {
        if (k < s2) red[k] += red[k + s2];
        __syncthreads();
    }
    if (k == 0) {
        if (y == 0)      bias_n[j] = red[0] + nc0[j];
        else if (y == 1) atomicAdd(&biasPQ[j], red[0] + mc0[j]);
        else             atomicAdd(&biasPQ[j], red[0]);
    }
}

// BN1 fold, 2 weight sets in one launch (blockIdx.y): node (inv1) / msg (invM)
__global__ __launch_bounds__(256) void k_fold1(const float* __restrict__ nW1, const float* __restrict__ ng1,
                                               const float* __restrict__ nb1, const float* __restrict__ nc1,
                                               const float* __restrict__ mW1, const float* __restrict__ mg1,
                                               const float* __restrict__ mb1, const float* __restrict__ mc1,
                                               const float* __restrict__ shn_s, const float* __restrict__ shn_q,
                                               const float* __restrict__ shm_s, const float* __restrict__ shm_q,
                                               unsigned short* __restrict__ A1n, float* __restrict__ b1n,
                                               unsigned short* __restrict__ A1m, float* __restrict__ b1m) {
    const int j = blockIdx.x;      // 0..255
    const int y = blockIdx.y;      // 0..1
    const int t = threadIdx.x;
    const float* W  = y ? mW1 : nW1;
    const float* g  = y ? mg1 : ng1;
    const float* b  = y ? mb1 : nb1;
    const float* cv = y ? mc1 : nc1;
    const float* ss = y ? shm_s : shn_s;
    const float* sq = y ? shm_q : shn_q;
    unsigned short* Bt = y ? A1m : A1n;
    float* bias = y ? b1m : b1n;
    const float inv = y ? (1.f / 196608.f) : (1.f / 65536.f);
    float part = 0.f;
    for (int k = t; k < 512; k += 256) {
        float mu  = ss[k] * inv;
        float var = sq[k] * inv - mu * mu;
        float s   = g[k] * rsqrtf(var + 1e-5f);
        float tt  = b[k] - mu * s;
        float wv  = W[(size_t)k * 256 + j];
        Bt[(size_t)j * 512 + k] = f2bu(s * wv);
        part += tt * wv;
    }
    __shared__ float red[256];
    red[t] = part;
    __syncthreads();
    for (int s2 = 128; s2 > 0; s2 >>= 1) {
        if (t < s2) red[t] += red[t + s2];
        __syncthreads();
    }
    if (t == 0) bias[j] = red[0] + cv[j];
}

// generic fold (final MLP): Bt[j][k] = s_k*W[k][j]; bias[j] = red + cvec[j]
__global__ __launch_bounds__(256) void k_fold(const float* __restrict__ W,      // [Kc][N]
                                              const float* __restrict__ gamma,
                                              const float* __restrict__ beta,
                                              const float* __restrict__ ssum,
                                              const float* __restrict__ ssq,
                                              const float* __restrict__ cvec,
                                              float inv_count, int N, int Kc,
                                              unsigned short* __restrict__ Bt,  // [N][Kc]
                                              float* __restrict__ bias, int bias_add) {
    const int j = blockIdx.x;
    const int t = threadIdx.x;
    float part = 0.f;
    for (int k = t; k < Kc; k += 256) {
        float mu  = ssum[k] * inv_count;
        float var = ssq[k] * inv_count - mu * mu;
        float s   = gamma[k] * rsqrtf(var + 1e-5f);
        float tt  = beta[k] - mu * s;
        float w   = W[(size_t)k * N + j];
        Bt[(size_t)j * Kc + k] = f2bu(s * w);
        part += tt * w;
    }
    __shared__ float red[256];
    red[t] = part;
    __syncthreads();
    for (int s2 = 128; s2 > 0; s2 >>= 1) {
        if (t < s2) red[t] += red[t + s2];
        __syncthreads();
    }
    if (t == 0) {
        if (bias_add) atomicAdd(&bias[j], red[0]);
        else bias[j] = red[0] + cvec[j];
    }
}

// 128x128-tile bf16 MFMA GEMM, A [M][lda] bf16, Bt [N][K] bf16.
// global_load_lds width=16 staging, 3-buffer counted-vmcnt pipeline.
// EPI: 1 bias+relu+stats bf16; 2 bias+sigmoid+stats bf16; 4 bias+sigmoid f32
template <int EPI>
__global__ __launch_bounds__(256) void k_gemm(const unsigned short* __restrict__ A, int lda,
                                              const unsigned short* __restrict__ Bt,
                                              void* __restrict__ C, int ldc,
                                              const float* __restrict__ bias,
                                              float* __restrict__ ssum, float* __restrict__ ssq,
                                              int K) {
    const int n0 = blockIdx.x * 128;
    const int m0 = blockIdx.y * 128;
    const int tid = threadIdx.x;
    const int w = tid >> 6;
    const int lane = tid & 63;
    const int q = lane >> 4;
    const int l = lane & 15;
    const int wm = w >> 1;
    const int wn = w & 1;

    __shared__ __align__(16) unsigned short lA[3][128 * 32];  // [m][k]
    __shared__ __align__(16) unsigned short lB[3][128 * 32];  // [n][k]
    __shared__ float s_sum[128];
    __shared__ float s_sq[128];

    if ((EPI == 1 || EPI == 2) && tid < 128) { s_sum[tid] = 0.f; s_sq[tid] = 0.f; }

    f32x4 acc[4][4] = {};

    const int rsub = tid >> 2;          // 0..63
    const int ksub = (tid & 3) * 8;     // 0,8,16,24
    const unsigned short* gA = A + (size_t)(m0 + rsub) * lda + ksub;
    const unsigned short* gB = Bt + (size_t)(n0 + rsub) * K + ksub;
    const unsigned wofs = (unsigned)(tid >> 6) * 1024;  // wave LDS base, bytes

    auto stage = [&](int buf, int k0) {   // 4 DMA ops per wave
        char* la = (char*)lA[buf] + wofs;
        char* lb = (char*)lB[buf] + wofs;
        gld16(gA + k0, la);
        gld16(gA + (size_t)64 * lda + k0, la + 4096);
        gld16(gB + k0, lb);
        gld16(gB + (size_t)64 * K + k0, lb + 4096);
    };

    const int nt = K >> 5;
    stage(0, 0);
    if (nt > 1) stage(1, 32);

    int cur = 0;
    for (int t = 0; t < nt; ++t) {
        if (t + 1 < nt) { asm volatile("s_waitcnt vmcnt(4)" ::: "memory"); }
        else            { asm volatile("s_waitcnt vmcnt(0)" ::: "memory"); }
        __builtin_amdgcn_s_barrier();
        __builtin_amdgcn_sched_barrier(0);
        if (t + 2 < nt) {
            int b2 = cur + 2; if (b2 >= 3) b2 -= 3;
            stage(b2, (t + 2) << 5);   // overwrites buf t-1: safe, all reads done
        }
        short8 av[4], bv[4];
#pragma unroll
        for (int i = 0; i < 4; ++i)
            av[i] = *(const short8*)(&lA[cur][(wm * 64 + i * 16 + l) * 32 + q * 8]);
#pragma unroll
        for (int j = 0; j < 4; ++j)
            bv[j] = *(const short8*)(&lB[cur][(wn * 64 + j * 16 + l) * 32 + q * 8]);
#pragma unroll
        for (int i = 0; i < 4; ++i)
#pragma unroll
            for (int j = 0; j < 4; ++j)
                acc[i][j] = __builtin_amdgcn_mfma_f32_16x16x32_bf16(av[i], bv[j], acc[i][j], 0, 0, 0);
        cur = (cur == 2) ? 0 : cur + 1;
    }

#pragma unroll
    for (int j = 0; j < 4; ++j) {
        const int colL = wn * 64 + j * 16 + l;
        const int col = n0 + colL;
        const float bb = bias[col];
        float psum = 0.f, psq = 0.f;
#pragma unroll
        for (int i = 0; i < 4; ++i) {
            const int rowL = wm * 64 + i * 16 + q * 4;
#pragma unroll
            for (int r = 0; r < 4; ++r) {
                float v = acc[i][j][r] + bb;
                if (EPI == 1) v = fmaxf(v, 0.f);
                if (EPI == 2 || EPI == 4) v = sigmoidf_(v);
                const size_t off = (size_t)(m0 + rowL + r) * ldc + col;
                if (EPI == 4) ((float*)C)[off] = v;
                else ((unsigned short*)C)[off] = f2bu(v);
                psum += v; psq += v * v;
            }
        }
        if (EPI == 1 || EPI == 2) {
            atomicAdd(&s_sum[colL], psum);
            atomicAdd(&s_sq[colL], psq);
        }
    }
    if (EPI == 1 || EPI == 2) {
        __syncthreads();
        if (tid < 128) {
            atomicAdd(&ssum[n0 + tid], s_sum[tid]);
            atomicAdd(&ssq[n0 + tid], s_sq[tid]);
        }
    }
}

// Dual-tile PQ GEMM + fused h_m stats.
template <int STATS>
__global__ __launch_bounds__(256) void k_gemm_pq(const unsigned short* __restrict__ A,   // x16 chunk [G][256]
                                                 const unsigned short* __restrict__ Bt,  // Btm [1024][256]
                                                 unsigned short* __restrict__ PQ,        // [G][1024]
                                                 const float* __restrict__ biasP,        // biasPQ [512]
                                                 float* __restrict__ ssum,               // shm_s
                                                 float* __restrict__ ssq) {              // shm_q
    const int K = 256;
    const int f0 = blockIdx.x * 128;
    const int m0 = blockIdx.y * 128;
    const int tid = threadIdx.x;
    const int w = tid >> 6;
    const int lane = tid & 63;
    const int q = lane >> 4;
    const int l = lane & 15;
    const int wm = w >> 1;
    const int wn = w & 1;

    __shared__ __align__(16) unsigned short lA[2][128 * 32];  // 8 KB each
    __shared__ __align__(16) unsigned short lB[2][256 * 32];  // 16 KB each
    __shared__ float s_sum[128];
    __shared__ float s_sq[128];

    if (STATS && tid < 128) { s_sum[tid] = 0.f; s_sq[tid] = 0.f; }

    f32x4 accP[4][4] = {};
    f32x4 accQ[4][4] = {};

    const int rsub = tid >> 2;          // 0..63
    const int ksub = (tid & 3) * 8;     // 0,8,16,24
    const unsigned short* gA  = A  + (size_t)(m0 + rsub) * 256 + ksub;
    const unsigned short* gBP = Bt + (size_t)(f0 + rsub) * K + ksub;
    const unsigned short* gBQ = Bt + (size_t)(512 + f0 + rsub) * K + ksub;
    const unsigned wofs = (unsigned)w * 1024;

    auto stage = [&](int buf, int k0) {   // 6 DMA ops per wave
        char* la = (char*)lA[buf] + wofs;
        char* lb = (char*)lB[buf] + wofs;
        gld16(gA + k0, la);
        gld16(gA + (size_t)64 * 256 + k0, la + 4096);
        gld16(gBP + k0, lb);
        gld16(gBP + (size_t)64 * K + k0, lb + 4096);
        gld16(gBQ + k0, lb + 8192);
        gld16(gBQ + (size_t)64 * K + k0, lb + 12288);
    };

    stage(0, 0);
    pipe_barrier();

    const int nt = K >> 5;  // 8
    int cur = 0;
    for (int t = 0; t < nt; ++t) {
        if (t + 1 < nt) stage(cur ^ 1, (t + 1) << 5);  // DMA lands during MFMA
        short8 av[4], bvP[4], bvQ[4];
#pragma unroll
        for (int i = 0; i < 4; ++i)
            av[i] = *(const short8*)(&lA[cur][(wm * 64 + i * 16 + l) * 32 + q * 8]);
#pragma unroll
        for (int j = 0; j < 4; ++j) {
            bvP[j] = *(const short8*)(&lB[cur][(wn * 64 + j * 16 + l) * 32 + q * 8]);
            bvQ[j] = *(const short8*)(&lB[cur][(128 + wn * 64 + j * 16 + l) * 32 + q * 8]);
        }
#pragma unroll
        for (int i = 0; i < 4; ++i)
#pragma unroll
            for (int j = 0; j < 4; ++j) {
                accP[i][j] = __builtin_amdgcn_mfma_f32_16x16x32_bf16(av[i], bvP[j], accP[i][j], 0, 0, 0);
                accQ[i][j] = __builtin_amdgcn_mfma_f32_16x16x32_bf16(av[i], bvQ[j], accQ[i][j], 0, 0, 0);
            }
        if (t + 1 < nt) pipe_barrier();
        cur ^= 1;
    }

#pragma unroll
    for (int j = 0; j < 4; ++j) {
        const int colL = wn * 64 + j * 16 + l;   // 0..127
        const int f = f0 + colL;
        const float bb = biasP[f];
        float s = 0.f, qq = 0.f;
#pragma unroll
        for (int i = 0; i < 4; ++i) {
            const int rowb = m0 + wm * 64 + i * 16 + q * 4;   // %4==0: one graph
            float p[4], qv[4];
#pragma unroll
            for (int r = 0; r < 4; ++r) {
                p[r]  = accP[i][j][r] + bb;
                qv[r] = accQ[i][j][r];
                PQ[(size_t)(rowb + r) * 1024 + f]       = f2bu(p[r]);
                PQ[(size_t)(rowb + r) * 1024 + 512 + f] = f2bu(qv[r]);
            }
            if (STATS) {
#pragma unroll
                for (int si = 0; si < 4; ++si)
#pragma unroll
                    for (int di = 0; di < 4; ++di) {
                        if (si == di) continue;
                        float v = fmaxf(p[si] + qv[di], 0.f);
                        s += v; qq += v * v;
                    }
            }
        }
        if (STATS) {
            atomicAdd(&s_sum[colL], s);
            atomicAdd(&s_sq[colL], qq);
        }
    }
    if (STATS) {
        __syncthreads();
        if (tid < 128) {
            atomicAdd(&ssum[f0 + tid], s_sum[tid]);
            atomicAdd(&ssq[f0 + tid], s_sq[tid]);
        }
    }
}

// Fused message GEMM + in-register mean + bf16 store + column stats.
// 128x256 tile, wave grid 2x2, acc[4][8] (the proven msg4: 112 VGPR,
// 50 KB LDS, 3 blocks/CU). Padded M: row m = 4*node + slot, slot 3 = pad.
__global__ __launch_bounds__(256) void k_gemm_msg4(const unsigned short* __restrict__ PQ,  // [G][1024] chunk-local
                                                   const unsigned short* __restrict__ Bt,  // A1m [256][512]
                                                   unsigned short* __restrict__ inf_,      // chunk-offset, [G][512] bf16
                                                   const float* __restrict__ bias,         // b1m [256]
                                                   float* __restrict__ ssum,               // sif_s+256
                                                   float* __restrict__ ssq) {              // sif_q+256
    const int K = 512;
    const int m0 = blockIdx.x * 128;          // padded chunk-local msg row base
    const int tid = threadIdx.x;
    const int w = tid >> 6;
    const int lane = tid & 63;
    const int q = lane >> 4;
    const int l = lane & 15;
    const int wm = w >> 1;                    // row half
    const int wn = w & 1;                     // col half (128 cols each)

    __shared__ __align__(16) unsigned short lA[2][128 * 32];  // 8 KB each
    __shared__ __align__(16) unsigned short lB[2][256 * 32];  // 16 KB each
    __shared__ float s_sum[256];
    __shared__ float s_sq[256];

    s_sum[tid] = 0.f; s_sq[tid] = 0.f;

    f32x4 acc[4][8] = {};

    const int rsub = tid >> 2;          // 0..63
    const int ksub = (tid & 3) * 8;     // 0,8,16,24
    unsigned aP[2], aQ[2], wAo[2];
    bool pad[2];
#pragma unroll
    for (int t = 0; t < 2; ++t) {
        int row = m0 + t * 64 + rsub;    // padded chunk-local msg row
        int node = row >> 2;             // chunk-local node
        int slot = row & 3;
        pad[t] = (slot == 3);
        int si = node & 3;
        int di = slot + (slot >= si ? 1 : 0);
        aP[t] = (unsigned)node * 1024 + ksub;
        aQ[t] = (unsigned)(node - si + di) * 1024 + 512 + ksub;
        wAo[t] = (unsigned)((t * 64 + rsub) * 32 + ksub);
    }
    const unsigned short* gB = Bt + (size_t)rsub * K + ksub;
    const unsigned wofs = (unsigned)w * 1024;

    auto loadPQ = [&](int k0, short8 p8[2], short8 q8[2]) {
#pragma unroll
        for (int t = 0; t < 2; ++t) {
            if (!pad[t]) {
                p8[t] = *(const short8*)(PQ + aP[t] + k0);
                q8[t] = *(const short8*)(PQ + aQ[t] + k0);
            }
        }
    };
    auto buildA = [&](const short8 p8[2], const short8 q8[2], short8 a8[2]) {
#pragma unroll
        for (int t = 0; t < 2; ++t) {
            if (!pad[t]) {
                u32x4 pu = __builtin_bit_cast(u32x4, p8[t]);
                u32x4 qu = __builtin_bit_cast(u32x4, q8[t]);
                u32x4 ou;
#pragma unroll
                for (int i = 0; i < 4; ++i) {
                    float pl = __uint_as_float(pu[i] << 16);
                    float ph = __uint_as_float(pu[i] & 0xffff0000u);
                    float ql = __uint_as_float(qu[i] << 16);
                    float qh = __uint_as_float(qu[i] & 0xffff0000u);
                    float sl = fmaxf(pl + ql, 0.f);
                    float sh = fmaxf(ph + qh, 0.f);
                    unsigned r;
                    asm("v_cvt_pk_bf16_f32 %0, %1, %2" : "=v"(r) : "v"(sl), "v"(sh));
                    ou[i] = r;
                }
                a8[t] = __builtin_bit_cast(short8, ou);
            } else {
                short8 z = {};
                a8[t] = z;
            }
        }
    };
    auto stageB = [&](int buf, int k0) {   // 256 rows per K-step
        char* lb = (char*)lB[buf] + wofs;
#pragma unroll
        for (int t = 0; t < 4; ++t)
            gld16(gB + (size_t)(t * 64) * K + k0, lb + t * 4096);
    };

    // prologue: tile 0
    {
        short8 p8[2], q8[2], a8[2];
        loadPQ(0, p8, q8);
        buildA(p8, q8, a8);
        *(short8*)(&lA[0][wAo[0]]) = a8[0];
        *(short8*)(&lA[0][wAo[1]]) = a8[1];
        stageB(0, 0);
    }
    pipe_barrier();

    const int nt = K >> 5;  // 16
    int cur = 0;
    for (int t = 0; t < nt; ++t) {
        short8 p8[2], q8[2];
        if (t + 1 < nt) {
            loadPQ((t + 1) << 5, p8, q8);   // issue early; consumed after MFMA
            stageB(cur ^ 1, (t + 1) << 5);  // DMA, lands during MFMA
        }
        short8 av[4], bv[8];
#pragma unroll
        for (int i = 0; i < 4; ++i)
            av[i] = *(const short8*)(&lA[cur][(wm * 64 + i * 16 + l) * 32 + q * 8]);
#pragma unroll
        for (int j = 0; j < 8; ++j)
            bv[j] = *(const short8*)(&lB[cur][(wn * 128 + j * 16 + l) * 32 + q * 8]);
#pragma unroll
        for (int i = 0; i < 4; ++i)
#pragma unroll
            for (int j = 0; j < 8; ++j)
                acc[i][j] = __builtin_amdgcn_mfma_f32_16x16x32_bf16(av[i], bv[j], acc[i][j], 0, 0, 0);
        if (t + 1 < nt) {
            short8 a8[2];
            buildA(p8, q8, a8);
            *(short8*)(&lA[cur ^ 1][wAo[0]]) = a8[0];
            *(short8*)(&lA[cur ^ 1][wAo[1]]) = a8[1];
            pipe_barrier();
        }
        cur ^= 1;
    }

#pragma unroll
    for (int j = 0; j < 8; ++j) {
        const int colL = wn * 128 + j * 16 + l;
        const float bb = bias[colL];
        float psum = 0.f, psq = 0.f;
#pragma unroll
        for (int i = 0; i < 4; ++i) {
            const int g = (m0 >> 2) + wm * 16 + i * 4 + q;   // chunk-local node row
            float s0 = sigmoidf_(acc[i][j][0] + bb);
            float s1 = sigmoidf_(acc[i][j][1] + bb);
            float s2 = sigmoidf_(acc[i][j][2] + bb);
            float vm = (s0 + s1 + s2) * (1.f / 3.f);
            inf_[(size_t)g * 512 + 256 + colL] = f2bu(vm);
            psum += vm; psq += vm * vm;
        }
        atomicAdd(&s_sum[colL], psum);
        atomicAdd(&s_sq[colL], psq);
    }
    __syncthreads();
    atomicAdd(&ssum[tid], s_sum[tid]);
    atomicAdd(&ssq[tid], s_sq[tid]);
}

extern "C" void kernel_launch(void* const* d_in, const int* in_sizes, int n_in,
                              void* d_out, int out_size, void* d_ws, size_t ws_size,
                              hipStream_t stream) {
    const float* x   = (const float*)d_in[0];
    const float* ng0 = (const float*)d_in[1];
    const float* nb0 = (const float*)d_in[2];
    const float* nW0 = (const float*)d_in[3];
    const float* nc0 = (const float*)d_in[4];
    const float* ng1 = (const float*)d_in[5];
    const float* nb1 = (const float*)d_in[6];
    const float* nW1 = (const float*)d_in[7];
    const float* nc1 = (const float*)d_in[8];
    const float* mg0 = (const float*)d_in[9];
    const float* mb0 = (const float*)d_in[10];
    const float* mW0 = (const float*)d_in[11];
    const float* mc0 = (const float*)d_in[12];
    const float* mg1 = (const float*)d_in[13];
    const float* mb1 = (const float*)d_in[14];
    const float* mW1 = (const float*)d_in[15];
    const float* mc1 = (const float*)d_in[16];
    const float* fg0 = (const float*)d_in[17];
    const float* fb0 = (const float*)d_in[18];
    const float* fW0 = (const float*)d_in[19];
    const float* fc0 = (const float*)d_in[20];
    const float* fg1 = (const float*)d_in[21];
    const float* fb1 = (const float*)d_in[22];
    const float* fW1 = (const float*)d_in[23];
    const float* fc1 = (const float*)d_in[24];

    char* ws = (char*)d_ws;
    const size_t MiB = 1024 * 1024;

    // chunk count for PQ: peak ws = 100 + 128/Cq MiB (x16 adds 32 MiB)
    int Cq = 1;
    while (Cq < 8 && (100 + 128 / Cq) * MiB > ws_size) Cq *= 2;
    const int G = 65536 / Cq;  // node rows per chunk (multiple of 128)

    // header [0,4MiB): stats (zeroed) + biases + folded weights
    float* stat = (float*)ws;
    float* sx_s   = stat + 0;     // 256
    float* sx_q   = stat + 256;   // 256
    float* shn_s  = stat + 512;   // 512
    float* shn_q  = stat + 1024;
    float* shm_s  = stat + 1536;
    float* shm_q  = stat + 2048;
    float* sif_s  = stat + 2560;
    float* sif_q  = stat + 3072;
    float* shf_s  = stat + 3584;
    float* shf_q  = stat + 4096;  // -> 4608
    float* biasPQ = stat + 4608;  // 1024, upper 512 stay zero
    // zeroed region ends at 5632 floats
    float* bias_n = stat + 5632;  // 512
    float* b1n    = stat + 6144;  // 256
    float* b1m    = stat + 6400;  // 256
    float* b0f    = stat + 6656;  // 512
    float* b1f    = stat + 7168;  // 256

    unsigned short* An  = (unsigned short*)(ws + 256 * 1024);  // [512][256]
    unsigned short* Btm = An + 512 * 256;                      // [1024][256]
    unsigned short* A1n = Btm + 1024 * 256;                    // [256][512]
    unsigned short* A1m = A1n + 256 * 512;                     // [256][512]
    unsigned short* A0f = A1m + 256 * 512;                     // [512][512]
    unsigned short* A1f = A0f + 512 * 512;                     // [256][512]

    // [4,68): hn (bf16, live gemm1..gemm2n) -> hf (bf16, live gemm3..gemm4)
    // [68, 68+128/Cq): PQ chunk buffer
    // [68+128/Cq, +32): x16 bf16 [65536][256]
    unsigned short* hn    = (unsigned short*)(ws + 4 * MiB);
    unsigned short* hf    = (unsigned short*)(ws + 4 * MiB);
    unsigned short* PQbuf = (unsigned short*)(ws + 68 * MiB);
    unsigned short* x16   = (unsigned short*)(ws + (68 + 128 / Cq) * MiB);
    unsigned short* inf   = (unsigned short*)d_out;  // [65536,512] bf16, dead before gemm4

    const float inv1 = 1.f / 65536.f;

    // zero stats + biasPQ (5632 floats = 1408 float4)
    k_zero4<<<6, 256, 0, stream>>>((float4*)stat, 1408);

    // x -> bf16 + column stats (fused)
    k_xcvt<<<1024, 256, 0, stream>>>(x, x16, sx_s, sx_q);

    // fold BN0: 3 weight sets in one launch (msg BN0 stats == node BN0 stats:
    // each node appears exactly 3x as src and 3x as dst across the 12 pairs)
    k_fold0<<<dim3(512, 3), 256, 0, stream>>>(nW0, ng0, nb0, nc0, mW0, mg0, mb0, mc0,
                                              sx_s, sx_q, An, bias_n, Btm, biasPQ);

    // h_n = relu(x16 @ An + bias_n), BN1_n stats
    k_gemm<1><<<dim3(4, 512), 256, 0, stream>>>(x16, 256, An, hn, 512, bias_n, shn_s, shn_q, 256);

    // PQ chunks: dual-tile P/Q GEMM with fused h_m stats
    for (int c = 0; c < Cq; ++c) {
        k_gemm_pq<1><<<dim3(4, G / 128), 256, 0, stream>>>(
            x16 + (size_t)c * G * 256, Btm, PQbuf, biasPQ, shm_s, shm_q);
    }

    // fold BN1: both sets in one launch
    k_fold1<<<dim3(256, 2), 256, 0, stream>>>(nW1, ng1, nb1, nc1, mW1, mg1, mb1, mc1,
                                              shn_s, shn_q, shm_s, shm_q, A1n, b1n, A1m, b1m);

    // x_agg FIRST (PQ still L3-resident from its writer): padded msg GEMM ->
    // in_f[:,256:512] bf16 + f-BN0 stats (cols 256..511)
    for (int c = 0; c < Cq; ++c) {
        if (Cq > 1)  // recompute PQ chunk without stats (Cq==1 kept the full PQ)
            k_gemm_pq<0><<<dim3(4, G / 128), 256, 0, stream>>>(
                x16 + (size_t)c * G * 256, Btm, PQbuf, biasPQ, nullptr, nullptr);
        k_gemm_msg4<<<dim3(G / 32), 256, 0, stream>>>(
            PQbuf, A1m, inf + (size_t)c * G * 512, b1m, sif_s + 256, sif_q + 256);
    }

    // x_node = sigmoid(hn @ A1n + b1n) -> in_f[:,0:256] (in d_out), f-BN0 stats
    k_gemm<2><<<dim3(2, 512), 256, 0, stream>>>(hn, 512, A1n, inf, 512, b1n, sif_s, sif_q, 512);

    // final MLP
    k_fold<<<512, 256, 0, stream>>>(fW0, fg0, fb0, sif_s, sif_q, fc0, inv1, 512, 512, A0f, b0f, 0);
    k_gemm<1><<<dim3(4, 512), 256, 0, stream>>>(inf, 512, A0f, hf, 512, b0f, shf_s, shf_q, 512);
    k_fold<<<256, 256, 0, stream>>>(fW1, fg1, fb1, shf_s, shf_q, fc1, inv1, 256, 512, A1f, b1f, 0);
    k_gemm<4><<<dim3(2, 512), 256, 0, stream>>>(hf, 512, A1f, d_out, 256, b1f, nullptr, nullptr, 512);

    (void)in_sizes; (void)n_in; (void)out_size;
}